// Round 6
// baseline (280.404 us; speedup 1.0000x reference)
//
#include <hip/hip_runtime.h>

typedef unsigned short u16;
typedef u16 u16x8 __attribute__((ext_vector_type(8)));
typedef u16 u16x4 __attribute__((ext_vector_type(4)));
typedef unsigned u32x4 __attribute__((ext_vector_type(4)));
typedef float f32x4 __attribute__((ext_vector_type(4)));
typedef float f32x16 __attribute__((ext_vector_type(16)));
typedef __bf16 bf16x8 __attribute__((ext_vector_type(8)));

// SCALE * log2(e): softmax computed in exp2 domain, folded into Q at GEMM1.
#define QSCALE_LOG2E 0.18033688011112042f

__device__ __forceinline__ u16 cvt_bf16(float f) {
  __bf16 h = (__bf16)f;
  return __builtin_bit_cast(u16, h);
}

__device__ __forceinline__ void gl_lds16(const void* g, void* l) {
  __builtin_amdgcn_global_load_lds(
      (const __attribute__((address_space(1))) void*)g,
      (__attribute__((address_space(3))) void*)l, 16, 0, 0);
}

#define SBAR() __builtin_amdgcn_s_barrier()
#define SCHED0() __builtin_amdgcn_sched_barrier(0)
#define VMCNT2() asm volatile("s_waitcnt vmcnt(2)" ::: "memory")
#define VMCNT0() asm volatile("s_waitcnt vmcnt(0)" ::: "memory")
#define PRIO1() __builtin_amdgcn_s_setprio(1)
#define PRIO0() __builtin_amdgcn_s_setprio(0)

// ---------------- cast fp32 -> bf16, 8 elems/thread ----------------
__global__ __launch_bounds__(256) void cast_f32_bf16(const float* __restrict__ in,
                                                     u16* __restrict__ out) {
  long i = ((long)blockIdx.x * 256 + threadIdx.x) * 8;
  f32x4 a = *(const f32x4*)(in + i);
  f32x4 b = *(const f32x4*)(in + i + 4);
  u16x8 o;
  o[0] = cvt_bf16(a[0]); o[1] = cvt_bf16(a[1]); o[2] = cvt_bf16(a[2]); o[3] = cvt_bf16(a[3]);
  o[4] = cvt_bf16(b[0]); o[5] = cvt_bf16(b[1]); o[6] = cvt_bf16(b[2]); o[7] = cvt_bf16(b[3]);
  *(u16x8*)(out + i) = o;
}

// ============ GEMM1: 256x256 tile, BK=64, 8-phase counted-vmcnt ============
// C = A * B^T, A[8192][1024], B[3072][1024] (w_qkv). 8 waves (2Mx4N),
// wave tile 128x64 (M_rep 8 x N_rep 4). LDS 128 KiB: [dbuf][half][128][64]
// for A and B, XOR-swizzled (16B slot ^= row&7) via pre-swizzled gl_lds
// source; reads apply the same XOR. d0 holds even K-tiles, d1 odd.
// Iter i: phases 0-3 compute kt=2i from d0 while staging kt=2i+1 -> d1
// (one half-tile = 2 gl_lds per phase); phases 4-7 compute 2i+1 from d1
// while staging 2i+2 -> d0. vmcnt(2) at p0/p4 (after that phase's issue)
// guarantees everything older is landed; refill of a dbuf is issued only
// after its last read phase, so in-flight landing is always safe.
// Epilogue: bn<1024 -> Q (pre-scaled); <2048 -> K; else V TRANSPOSED into
// Vt[bh*64+d][2048].
__global__ __launch_bounds__(512, 2) void gemm1_8p(
    const u16* __restrict__ A, const u16* __restrict__ Bw,
    u16* __restrict__ Cb, u16* __restrict__ Vt) {
  constexpr int K = 1024;
  __shared__ __align__(16) u16 sA[2][2][8192];   // [dbuf][mhalf][128*64]
  __shared__ __align__(16) u16 sB[2][2][8192];

  const int t = threadIdx.x;
  const int w = t >> 6, l = t & 63;
  const int fr = l & 15, fg = l >> 4;
  const int wm = w >> 2, wn = w & 3;

  // XCD-grouped decode: 384 blocks = 8 XCD x 48; by-fast within XCD so an
  // XCD's blocks share B-panels (L2 reuse). by in [xcd*4, xcd*4+4).
  const int bid = blockIdx.x;
  const int xcd = bid & 7, c = bid >> 3;          // c 0..47
  const int by = xcd * 4 + (c & 3), bx = c >> 2;  // by 0..31, bx 0..11
  const int bm = by * 256, bn = bx * 256;

  // staging source (pre-swizzled): thread t covers LDS row t>>3, slot t&7
  const int strow = t >> 3;                       // 0..63
  const int scol8 = (t & 7) ^ (strow & 7);
  const u16* gAs = A + (long)(bm + strow) * K + scol8 * 8;
  const u16* gBs = Bw + (long)(bn + strow) * K + scol8 * 8;

#define STAGE_PART(d, part, kt)                                          \
  do {                                                                   \
    const int mh_ = (part) & 1;                                          \
    const long off_ = (long)(mh_ * 128) * K + (long)(kt) * 64;           \
    if ((part) < 2) {                                                    \
      char* dst_ = (char*)&sA[d][mh_][0] + w * 1024;                     \
      gl_lds16(gAs + off_,          dst_);                               \
      gl_lds16(gAs + off_ + 64 * K, dst_ + 8192);                        \
    } else {                                                             \
      char* dst_ = (char*)&sB[d][mh_][0] + w * 1024;                     \
      gl_lds16(gBs + off_,          dst_);                               \
      gl_lds16(gBs + off_ + 64 * K, dst_ + 8192);                        \
    }                                                                    \
  } while (0)

  // frag reads (XOR-swizzled slots; conflict-free: slot = (kk*4+fg)^(fr&7))
#define LDA4(af, d, mq, kk)                                              \
  do {                                                                   \
    const u16* b_ = &sA[d][wm][0];                                       \
    _Pragma("unroll")                                                    \
    for (int mi_ = 0; mi_ < 4; ++mi_) {                                  \
      const int row_ = ((mq)*4 + mi_) * 16 + fr;                         \
      af[mi_] = *(const bf16x8*)&b_[row_ * 64 + ((((kk)*4 + fg) ^ (fr & 7)) * 8)]; \
    }                                                                    \
  } while (0)

#define LDB4(bf, d, kk)                                                  \
  do {                                                                   \
    const u16* b_ = &sB[d][wn >> 1][0];                                  \
    _Pragma("unroll")                                                    \
    for (int ni_ = 0; ni_ < 4; ++ni_) {                                  \
      const int row_ = (wn & 1) * 64 + ni_ * 16 + fr;                    \
      bf[ni_] = *(const bf16x8*)&b_[row_ * 64 + ((((kk)*4 + fg) ^ (fr & 7)) * 8)]; \
    }                                                                    \
  } while (0)

#define MFMA16(af, bf, mq)                                               \
  do {                                                                   \
    PRIO1();                                                             \
    _Pragma("unroll")                                                    \
    for (int mi_ = 0; mi_ < 4; ++mi_) {                                  \
      _Pragma("unroll")                                                  \
      for (int ni_ = 0; ni_ < 4; ++ni_)                                  \
        acc[(mq)*4 + mi_][ni_] = __builtin_amdgcn_mfma_f32_16x16x32_bf16( \
            af[mi_], bf[ni_], acc[(mq)*4 + mi_][ni_], 0, 0, 0);          \
    }                                                                    \
    PRIO0();                                                             \
  } while (0)

  f32x4 acc[8][4] = {};
  bf16x8 a4[4], b4[4];

  // prologue: stage kt0 -> d0 (8 loads). No wait needed yet.
  STAGE_PART(0, 0, 0); STAGE_PART(0, 1, 0); STAGE_PART(0, 2, 0); STAGE_PART(0, 3, 0);

  for (int it = 0; it < 8; ++it) {
    const int ktb = 2 * it + 1;
    const int ktn = 2 * it + 2;
    // ---- p0: compute d0(kt=2it) q(mq0,kk0); stage d1 part0 ----
    STAGE_PART(1, 0, ktb);
    VMCNT2(); SBAR(); SCHED0();
    LDB4(b4, 0, 0); LDA4(a4, 0, 0, 0);
    MFMA16(a4, b4, 0);
    SBAR();
    // ---- p1 ----
    LDA4(a4, 0, 1, 0);
    STAGE_PART(1, 1, ktb);
    SBAR();
    MFMA16(a4, b4, 1);
    SBAR();
    // ---- p2 ----
    LDB4(b4, 0, 1); LDA4(a4, 0, 0, 1);
    STAGE_PART(1, 2, ktb);
    SBAR();
    MFMA16(a4, b4, 0);
    SBAR();
    // ---- p3 ----
    LDA4(a4, 0, 1, 1);
    STAGE_PART(1, 3, ktb);
    SBAR();
    MFMA16(a4, b4, 1);
    SBAR();
    // ---- p4: compute d1(ktb) q(mq0,kk0); stage d0 part0 (kt=2it+2) ----
    if (it < 7) { STAGE_PART(0, 0, ktn); VMCNT2(); } else { VMCNT0(); }
    SBAR(); SCHED0();
    LDB4(b4, 1, 0); LDA4(a4, 1, 0, 0);
    MFMA16(a4, b4, 0);
    SBAR();
    // ---- p5 ----
    LDA4(a4, 1, 1, 0);
    if (it < 7) STAGE_PART(0, 1, ktn);
    SBAR();
    MFMA16(a4, b4, 1);
    SBAR();
    // ---- p6 ----
    LDB4(b4, 1, 1); LDA4(a4, 1, 0, 1);
    if (it < 7) STAGE_PART(0, 2, ktn);
    SBAR();
    MFMA16(a4, b4, 0);
    SBAR();
    // ---- p7 ----
    LDA4(a4, 1, 1, 1);
    if (it < 7) STAGE_PART(0, 3, ktn);
    SBAR();
    MFMA16(a4, b4, 1);
    SBAR();
  }

  // ---- epilogue ----
  const float cmul = (bn < 1024) ? QSCALE_LOG2E : 1.0f;
#pragma unroll
  for (int mi = 0; mi < 8; ++mi) {
    const int grow = bm + wm * 128 + mi * 16 + fg * 4;
#pragma unroll
    for (int ni = 0; ni < 4; ++ni) {
      const int gcol = bn + wn * 64 + ni * 16 + fr;
      if (bn < 2048) {
#pragma unroll
        for (int r = 0; r < 4; ++r)
          Cb[(long)(grow + r) * 2048 + gcol] = cvt_bf16(acc[mi][ni][r] * cmul);
      } else {
        const int d = gcol - 2048;           // 0..1023 -> (h, dl)
        const int bb = grow >> 11, nn = grow & 2047;
        u16x4 pk;
#pragma unroll
        for (int r = 0; r < 4; ++r) pk[r] = cvt_bf16(acc[mi][ni][r]);
        *(u16x4*)&Vt[((long)(bb * 16 + (d >> 6)) * 64 + (d & 63)) * 2048 + nn] = pk;
      }
    }
  }
#undef STAGE_PART
#undef LDA4
#undef LDB4
#undef MFMA16
}

// ---------------- NT GEMM (128x128, m97 structure) — used for proj ----
__global__ __launch_bounds__(256) void gemm_nt_proj(
    const u16* __restrict__ A, const u16* __restrict__ Bw,
    float* __restrict__ Cf, const float* __restrict__ bias) {
  constexpr int K = 1024;
  __shared__ __align__(16) u16 sA[128 * 32];
  __shared__ __align__(16) u16 sB[128 * 32];
  const int t = threadIdx.x;
  const int w = t >> 6, l = t & 63;
  const int fr = l & 15, fg = l >> 4;
  const int bm = blockIdx.y * 128, bn = blockIdx.x * 128;
  const int wr = (w >> 1) << 6, wc = (w & 1) << 6;

  f32x4 acc[4][4] = {};

  const int tr = t >> 2, tc = (t & 3) * 8;
  const u16* gA0 = A + (long)(bm + tr) * K + tc;
  const u16* gB0 = Bw + (long)(bn + tr) * K + tc;
  char* sAc = (char*)sA; char* sBc = (char*)sB;
  const int wb = w * 1024;

  for (int k0 = 0; k0 < K; k0 += 32) {
    gl_lds16(gA0 + k0,                 sAc + wb);
    gl_lds16(gA0 + (long)64 * K + k0,  sAc + 4096 + wb);
    gl_lds16(gB0 + k0,                 sBc + wb);
    gl_lds16(gB0 + (long)64 * K + k0,  sBc + 4096 + wb);
    __syncthreads();
    bf16x8 af[4], bf[4];
#pragma unroll
    for (int m = 0; m < 4; ++m)
      af[m] = *(const bf16x8*)&sA[(wr + m * 16 + fr) * 32 + fg * 8];
#pragma unroll
    for (int n = 0; n < 4; ++n)
      bf[n] = *(const bf16x8*)&sB[(wc + n * 16 + fr) * 32 + fg * 8];
#pragma unroll
    for (int m = 0; m < 4; ++m) {
#pragma unroll
      for (int n = 0; n < 4; ++n)
        acc[m][n] = __builtin_amdgcn_mfma_f32_16x16x32_bf16(af[m], bf[n], acc[m][n], 0, 0, 0);
    }
    __syncthreads();
  }

#pragma unroll
  for (int m = 0; m < 4; ++m) {
    const int grow = bm + wr + m * 16 + fg * 4;
#pragma unroll
    for (int n = 0; n < 4; ++n) {
      const int gcol = bn + wc + n * 16 + fr;
      float bv = bias[gcol];
#pragma unroll
      for (int r = 0; r < 4; ++r)
        Cf[(long)(grow + r) * 1024 + gcol] = acc[m][n][r] + bv;
    }
  }
}

// ---------------- flash attention: swapped-QK^T, in-register P ----------
__global__ __launch_bounds__(512, 4) void attn_fused(
    const u16* __restrict__ qk, const u16* __restrict__ vt,
    u16* __restrict__ ao) {
  const int t = threadIdx.x;
  const int w = t >> 6, l = t & 63;
  const int hi = l >> 5, ql = l & 31;
  const int bi = blockIdx.x;
  const int bh = (bi & 7) * 8 + ((bi >> 3) & 7);
  const int qt = bi >> 6;
  const int b = bh >> 4, h = bh & 15;
  const int qbase = qt * 256 + w * 32;

  __shared__ __align__(16) u16 sK[2][4096];
  __shared__ __align__(16) u16 sV[2][4096];
  __shared__ float sRed[8][32];

  bf16x8 qf[4];
  {
    const u16* qb = qk + (long)(b * 2048 + qbase + ql) * 2048 + h * 64 + hi * 8;
#pragma unroll
    for (int c = 0; c < 4; ++c) qf[c] = *(const bf16x8*)(qb + c * 16);
  }

  f32x16 acc0 = {}, acc1 = {};
  float mrow = -__builtin_inff(), lrow = 0.f;

  const int srow = w * 8 + (l >> 3);
  const int schunk = (l & 7) ^ (l >> 3);
  const u16* gKs = qk + (long)(b * 2048 + srow) * 2048 + 1024 + h * 64 + schunk * 8;
  const u16* gVs = vt + (long)(bh * 64 + srow) * 2048 + schunk * 8;
  char* sKc = (char*)sK; char* sVc = (char*)sV;
  const int wb = w * 1024;

  auto STAGE = [&](int buf, int kv0) {
    gl_lds16(gKs + (long)kv0 * 2048, sKc + buf * 8192 + wb);
    gl_lds16(gVs + kv0,              sVc + buf * 8192 + wb);
  };

  STAGE(0, 0);
  __syncthreads();
  int cur = 0;

  for (int ti = 0; ti < 32; ++ti) {
    if (ti < 31) STAGE(cur ^ 1, (ti + 1) * 64);

    f32x16 s0 = {}, s1 = {};
#pragma unroll
    for (int c = 0; c < 4; ++c) {
      bf16x8 kf = *(const bf16x8*)&sK[cur][(0 * 32 + ql) * 64 + (((2 * c + hi) ^ (l & 7)) * 8)];
      s0 = __builtin_amdgcn_mfma_f32_32x32x16_bf16(kf, qf[c], s0, 0, 0, 0);
    }
#pragma unroll
    for (int c = 0; c < 4; ++c) {
      bf16x8 kf = *(const bf16x8*)&sK[cur][(1 * 32 + ql) * 64 + (((2 * c + hi) ^ (l & 7)) * 8)];
      s1 = __builtin_amdgcn_mfma_f32_32x32x16_bf16(kf, qf[c], s1, 0, 0, 0);
    }

    float mloc = s0[0];
#pragma unroll
    for (int r = 1; r < 16; ++r) mloc = fmaxf(mloc, s0[r]);
#pragma unroll
    for (int r = 0; r < 16; ++r) mloc = fmaxf(mloc, s1[r]);
    mloc = fmaxf(mloc, __shfl_xor(mloc, 32));
    float nm = fmaxf(mrow, mloc);
    if (!__all(nm - mrow <= 8.0f)) {
      float al = __builtin_amdgcn_exp2f(mrow - nm);
      lrow *= al;
      mrow = nm;
      if (l < 32) sRed[w][ql] = al;
#pragma unroll
      for (int r = 0; r < 16; ++r) {
        float a2 = sRed[w][(r & 3) + 8 * (r >> 2) + 4 * hi];
        acc0[r] *= a2;
        acc1[r] *= a2;
      }
    }
    float ls = 0.f;
#pragma unroll
    for (int r = 0; r < 16; ++r) { float p = __builtin_amdgcn_exp2f(s0[r] - mrow); s0[r] = p; ls += p; }
#pragma unroll
    for (int r = 0; r < 16; ++r) { float p = __builtin_amdgcn_exp2f(s1[r] - mrow); s1[r] = p; ls += p; }
    ls += __shfl_xor(ls, 32);
    lrow += ls;

    bf16x8 pa[2][2];
    {
      unsigned W[8];
#pragma unroll
      for (int ii = 0; ii < 8; ++ii)
        asm("v_cvt_pk_bf16_f32 %0, %1, %2" : "=v"(W[ii]) : "v"(s0[2 * ii]), "v"(s0[2 * ii + 1]));
      asm("v_permlane32_swap_b32 %0, %1" : "+v"(W[0]), "+v"(W[2]));
      asm("v_permlane32_swap_b32 %0, %1" : "+v"(W[1]), "+v"(W[3]));
      asm("v_permlane32_swap_b32 %0, %1" : "+v"(W[4]), "+v"(W[6]));
      asm("v_permlane32_swap_b32 %0, %1" : "+v"(W[5]), "+v"(W[7]));
      u32x4 f0 = {W[0], W[1], W[2], W[3]}, f1 = {W[4], W[5], W[6], W[7]};
      pa[0][0] = __builtin_bit_cast(bf16x8, f0);
      pa[0][1] = __builtin_bit_cast(bf16x8, f1);
    }
    {
      unsigned W[8];
#pragma unroll
      for (int ii = 0; ii < 8; ++ii)
        asm("v_cvt_pk_bf16_f32 %0, %1, %2" : "=v"(W[ii]) : "v"(s1[2 * ii]), "v"(s1[2 * ii + 1]));
      asm("v_permlane32_swap_b32 %0, %1" : "+v"(W[0]), "+v"(W[2]));
      asm("v_permlane32_swap_b32 %0, %1" : "+v"(W[1]), "+v"(W[3]));
      asm("v_permlane32_swap_b32 %0, %1" : "+v"(W[4]), "+v"(W[6]));
      asm("v_permlane32_swap_b32 %0, %1" : "+v"(W[5]), "+v"(W[7]));
      u32x4 f0 = {W[0], W[1], W[2], W[3]}, f1 = {W[4], W[5], W[6], W[7]};
      pa[1][0] = __builtin_bit_cast(bf16x8, f0);
      pa[1][1] = __builtin_bit_cast(bf16x8, f1);
    }

#pragma unroll
    for (int kt = 0; kt < 2; ++kt) {
#pragma unroll
      for (int kc = 0; kc < 2; ++kc) {
        bf16x8 v0 = *(const bf16x8*)&sV[cur][(0 * 32 + ql) * 64 + (((4 * kt + 2 * kc + hi) ^ (l & 7)) * 8)];
        acc0 = __builtin_amdgcn_mfma_f32_32x32x16_bf16(pa[kt][kc], v0, acc0, 0, 0, 0);
        bf16x8 v1 = *(const bf16x8*)&sV[cur][(1 * 32 + ql) * 64 + (((4 * kt + 2 * kc + hi) ^ (l & 7)) * 8)];
        acc1 = __builtin_amdgcn_mfma_f32_32x32x16_bf16(pa[kt][kc], v1, acc1, 0, 0, 0);
      }
    }
    __syncthreads();
    cur ^= 1;
  }

  if (l < 32) sRed[w][ql] = 1.0f / lrow;
  __builtin_amdgcn_s_waitcnt(0);
#pragma unroll
  for (int r = 0; r < 16; ++r) {
    const int qr = (r & 3) + 8 * (r >> 2) + 4 * hi;
    const float inv = sRed[w][qr];
    u16* ob = ao + (long)(b * 2048 + qbase + qr) * 1024 + h * 64 + ql;
    ob[0]  = cvt_bf16(acc0[r] * inv);
    ob[32] = cvt_bf16(acc1[r] * inv);
  }
}

extern "C" void kernel_launch(void* const* d_in, const int* in_sizes, int n_in,
                              void* d_out, int out_size, void* d_ws, size_t ws_size,
                              hipStream_t stream) {
  const float* x     = (const float*)d_in[0];   // [4,2048,1024]
  const float* wqkv  = (const float*)d_in[1];   // [3072,1024]
  const float* wproj = (const float*)d_in[2];   // [1024,1024]
  const float* bproj = (const float*)d_in[3];   // [1024]
  float* out = (float*)d_out;

  u16* ws    = (u16*)d_ws;
  u16* xb    = ws;                    // 8388608  : x bf16 (dead after gemm1)
  u16* wqkvb = xb + 8388608;          // 3145728  : w_qkv bf16
  u16* wpb   = wqkvb + 3145728;       // 1048576  : w_proj bf16
  u16* qkb   = wpb + 1048576;         // 16777216 : [B*N][2048] Q|K bf16
  u16* vtb   = qkb + 16777216;        // 8388608  : [bh*64+d][2048] V^T bf16
  u16* aob   = xb;                    // aliases xb (x dead before attn writes)
  // peak 37748736 u16 = 75.5 MB

  cast_f32_bf16<<<4096, 256, 0, stream>>>(x, xb);
  cast_f32_bf16<<<1536, 256, 0, stream>>>(wqkv, wqkvb);
  cast_f32_bf16<<<512, 256, 0, stream>>>(wproj, wpb);

  gemm1_8p<<<384, 512, 0, stream>>>(xb, wqkvb, qkb, vtb);
  attn_fused<<<512, 512, 0, stream>>>(qkb, vtb, aob);
  gemm_nt_proj<<<dim3(8, 64), 256, 0, stream>>>(aob, wpb, out, bproj);
}

// Round 7
// 277.799 us; speedup vs baseline: 1.0094x; 1.0094x over previous
//
#include <hip/hip_runtime.h>

typedef unsigned short u16;
typedef u16 u16x8 __attribute__((ext_vector_type(8)));
typedef u16 u16x4 __attribute__((ext_vector_type(4)));
typedef unsigned u32x4 __attribute__((ext_vector_type(4)));
typedef float f32x4 __attribute__((ext_vector_type(4)));
typedef float f32x16 __attribute__((ext_vector_type(16)));
typedef __bf16 bf16x8 __attribute__((ext_vector_type(8)));

// SCALE * log2(e): softmax computed in exp2 domain, folded into Q at GEMM1.
#define QSCALE_LOG2E 0.18033688011112042f

__device__ __forceinline__ u16 cvt_bf16(float f) {
  __bf16 h = (__bf16)f;
  return __builtin_bit_cast(u16, h);
}

__device__ __forceinline__ void gl_lds16(const void* g, void* l) {
  __builtin_amdgcn_global_load_lds(
      (const __attribute__((address_space(1))) void*)g,
      (__attribute__((address_space(3))) void*)l, 16, 0, 0);
}

#define SBAR() __builtin_amdgcn_s_barrier()
#define SCHED0() __builtin_amdgcn_sched_barrier(0)
#define VMCNT6() asm volatile("s_waitcnt vmcnt(6)" ::: "memory")
#define VMCNT0() asm volatile("s_waitcnt vmcnt(0)" ::: "memory")
#define PRIO1() __builtin_amdgcn_s_setprio(1)
#define PRIO0() __builtin_amdgcn_s_setprio(0)

// ---------------- cast fp32 -> bf16, 8 elems/thread ----------------
__global__ __launch_bounds__(256) void cast_f32_bf16(const float* __restrict__ in,
                                                     u16* __restrict__ out) {
  long i = ((long)blockIdx.x * 256 + threadIdx.x) * 8;
  f32x4 a = *(const f32x4*)(in + i);
  f32x4 b = *(const f32x4*)(in + i + 4);
  u16x8 o;
  o[0] = cvt_bf16(a[0]); o[1] = cvt_bf16(a[1]); o[2] = cvt_bf16(a[2]); o[3] = cvt_bf16(a[3]);
  o[4] = cvt_bf16(b[0]); o[5] = cvt_bf16(b[1]); o[6] = cvt_bf16(b[2]); o[7] = cvt_bf16(b[3]);
  *(u16x8*)(out + i) = o;
}

// ============ GEMM1: 256x256, BK=64, m201-faithful 8-phase schedule ========
// C = A*B^T, A[8192][1024], B[3072][1024]. 8 waves; INTERLEAVED wave map:
// wave (wm,wn), quadrant (mh,nh) -> rows mh*128 + wm*64 +.., cols
// nh*128 + wn*32 +.. so each phase reads exactly one global A-half and one
// B-half; halves are refilled right after their last read phase (half-tile
// recycling in 2 LDS buffers). Stage calendar (iteration i, tiles 2i->buf0,
// 2i+1->buf1): ph0:A1[1]<-2i+1  ph1:B1[1]<-2i+1  ph2:A0[0]<-2i+2
// ph3:B0[0]<-2i+2  ph4:A0[1]<-2i+2  ph5:B0[1]<-2i+2  ph6:A1[0]<-2i+3
// ph7:B1[0]<-2i+3.  vmcnt(6) at ph0/ph4 only (after stage-issue, before
// barrier); issue->wait distance 4-6 phases. LDS 128 KiB, XOR-swizzled
// (slot ^= row&7) via pre-swizzled gl_lds source + same XOR on reads.
__global__ __launch_bounds__(512, 2) void gemm1_8p(
    const u16* __restrict__ A, const u16* __restrict__ Bw,
    u16* __restrict__ Cb, u16* __restrict__ Vt) {
  constexpr int K = 1024;
  __shared__ __align__(16) u16 sA[2][2][8192];   // [buf][half][128*64]
  __shared__ __align__(16) u16 sB[2][2][8192];

  const int t = threadIdx.x;
  const int w = t >> 6, l = t & 63;
  const int fr = l & 15, fg = l >> 4;
  const int wm = w >> 2, wn = w & 3;

  // XCD-grouped decode: 384 blocks = 8 XCD x 48; per XCD 4 consecutive by.
  const int bid = blockIdx.x;
  const int xcd = bid & 7, c = bid >> 3;
  const int by = xcd * 4 + (c & 3), bx = c >> 2;
  const int bm = by * 256, bn = bx * 256;

  // staging source (pre-swizzled): thread t covers LDS row t>>3, slot t&7
  const int strow = t >> 3;
  const int scol8 = (t & 7) ^ (strow & 7);
  const u16* gAs = A + (long)(bm + strow) * K + scol8 * 8;
  const u16* gBs = Bw + (long)(bn + strow) * K + scol8 * 8;

#define STAGE_A(bf_, mh_, kt_)                                           \
  do {                                                                   \
    char* d_ = (char*)&sA[bf_][mh_][0] + w * 1024;                       \
    const u16* s_ = gAs + (long)((mh_) * 128) * K + (long)(kt_) * 64;    \
    gl_lds16(s_,          d_);                                           \
    gl_lds16(s_ + 64 * K, d_ + 8192);                                    \
  } while (0)

#define STAGE_B(bf_, nh_, kt_)                                           \
  do {                                                                   \
    char* d_ = (char*)&sB[bf_][nh_][0] + w * 1024;                       \
    const u16* s_ = gBs + (long)((nh_) * 128) * K + (long)(kt_) * 64;    \
    gl_lds16(s_,          d_);                                           \
    gl_lds16(s_ + 64 * K, d_ + 8192);                                    \
  } while (0)

  // frag reads (swizzled slot = (kk*4+fg)^(fr&7)); A rows wm*64+mi*16+fr,
  // B rows wn*32+ni*16+fr (within the half's 128 rows).
#define READ_A(bf_, mh_)                                                 \
  do {                                                                   \
    const u16* p_ = &sA[bf_][mh_][0];                                    \
    _Pragma("unroll")                                                    \
    for (int mi_ = 0; mi_ < 4; ++mi_) {                                  \
      const int row_ = wm * 64 + mi_ * 16 + fr;                          \
      _Pragma("unroll")                                                  \
      for (int kk_ = 0; kk_ < 2; ++kk_)                                  \
        af[mi_][kk_] = *(const bf16x8*)&p_[row_ * 64 + (((kk_ * 4 + fg) ^ (fr & 7)) * 8)]; \
    }                                                                    \
  } while (0)

#define READ_B(bf_, nh_)                                                 \
  do {                                                                   \
    const u16* p_ = &sB[bf_][nh_][0];                                    \
    _Pragma("unroll")                                                    \
    for (int ni_ = 0; ni_ < 2; ++ni_) {                                  \
      const int row_ = wn * 32 + ni_ * 16 + fr;                          \
      _Pragma("unroll")                                                  \
      for (int kk_ = 0; kk_ < 2; ++kk_)                                  \
        bfr[nh_][ni_][kk_] = *(const bf16x8*)&p_[row_ * 64 + (((kk_ * 4 + fg) ^ (fr & 7)) * 8)]; \
    }                                                                    \
  } while (0)

#define MFMAQ(mh_, nh_)                                                  \
  do {                                                                   \
    PRIO1();                                                             \
    _Pragma("unroll")                                                    \
    for (int mi_ = 0; mi_ < 4; ++mi_) {                                  \
      _Pragma("unroll")                                                  \
      for (int ni_ = 0; ni_ < 2; ++ni_) {                                \
        _Pragma("unroll")                                                \
        for (int kk_ = 0; kk_ < 2; ++kk_)                                \
          acc[(mh_) * 4 + mi_][(nh_) * 2 + ni_] =                        \
              __builtin_amdgcn_mfma_f32_16x16x32_bf16(                   \
                  af[mi_][kk_], bfr[nh_][ni_][kk_],                      \
                  acc[(mh_) * 4 + mi_][(nh_) * 2 + ni_], 0, 0, 0);       \
      }                                                                  \
    }                                                                    \
    PRIO0();                                                             \
  } while (0)

  f32x4 acc[8][4] = {};
  bf16x8 af[4][2], bfr[2][2][2];

  // prologue: 6 half-pairs (t0 complete + t1's A[0],B[0]) = 12 gl_lds
  STAGE_A(0, 0, 0); STAGE_B(0, 0, 0); STAGE_A(0, 1, 0); STAGE_B(0, 1, 0);
  STAGE_A(1, 0, 1); STAGE_B(1, 0, 1);

  for (int i = 0; i < 7; ++i) {
    const int ktb = 2 * i + 1, ktn = 2 * i + 2, ktn1 = 2 * i + 3;
    // ph0
    STAGE_A(1, 1, ktb); VMCNT6(); SBAR(); SCHED0();
    READ_A(0, 0); READ_B(0, 0); MFMAQ(0, 0); SBAR();
    // ph1
    READ_B(0, 1); STAGE_B(1, 1, ktb); SBAR(); MFMAQ(0, 1); SBAR();
    // ph2
    READ_A(0, 1); STAGE_A(0, 0, ktn); SBAR(); MFMAQ(1, 0); SBAR();
    // ph3
    STAGE_B(0, 0, ktn); SBAR(); MFMAQ(1, 1); SBAR();
    // ph4
    STAGE_A(0, 1, ktn); VMCNT6(); SBAR(); SCHED0();
    READ_A(1, 0); READ_B(1, 0); MFMAQ(0, 0); SBAR();
    // ph5
    READ_B(1, 1); STAGE_B(0, 1, ktn); SBAR(); MFMAQ(0, 1); SBAR();
    // ph6
    READ_A(1, 1); STAGE_A(1, 0, ktn1); SBAR(); MFMAQ(1, 0); SBAR();
    // ph7
    STAGE_B(1, 0, ktn1); SBAR(); MFMAQ(1, 1); SBAR();
  }
  // final iteration (tiles 14 in buf0, 15 in buf1); no stages past tile 15
  STAGE_A(1, 1, 15); VMCNT6(); SBAR(); SCHED0();
  READ_A(0, 0); READ_B(0, 0); MFMAQ(0, 0); SBAR();
  READ_B(0, 1); STAGE_B(1, 1, 15); SBAR(); MFMAQ(0, 1); SBAR();
  READ_A(0, 1); SBAR(); MFMAQ(1, 0); SBAR();
  SBAR(); MFMAQ(1, 1); SBAR();
  VMCNT0(); SBAR(); SCHED0();
  READ_A(1, 0); READ_B(1, 0); MFMAQ(0, 0); SBAR();
  READ_B(1, 1); SBAR(); MFMAQ(0, 1); SBAR();
  READ_A(1, 1); SBAR(); MFMAQ(1, 0); SBAR();
  SBAR(); MFMAQ(1, 1); SBAR();

  // ---- epilogue (interleaved wave map) ----
  const float cmul = (bn < 1024) ? QSCALE_LOG2E : 1.0f;
#pragma unroll
  for (int mi = 0; mi < 8; ++mi) {
    const int mh = mi >> 2, mi_ = mi & 3;
    const int grow = bm + mh * 128 + wm * 64 + mi_ * 16 + fg * 4;
#pragma unroll
    for (int ni = 0; ni < 4; ++ni) {
      const int nh = ni >> 1, ni_ = ni & 1;
      const int gcol = bn + nh * 128 + wn * 32 + ni_ * 16 + fr;
      if (bn < 2048) {
#pragma unroll
        for (int r = 0; r < 4; ++r)
          Cb[(long)(grow + r) * 2048 + gcol] = cvt_bf16(acc[mi][ni][r] * cmul);
      } else {
        const int d = gcol - 2048;           // 0..1023 -> (h, dl)
        const int bb = grow >> 11, nn = grow & 2047;
        u16x4 pk;
#pragma unroll
        for (int r = 0; r < 4; ++r) pk[r] = cvt_bf16(acc[mi][ni][r]);
        *(u16x4*)&Vt[((long)(bb * 16 + (d >> 6)) * 64 + (d & 63)) * 2048 + nn] = pk;
      }
    }
  }
#undef STAGE_A
#undef STAGE_B
#undef READ_A
#undef READ_B
#undef MFMAQ
}

// ---------------- NT GEMM (128x128, m97 structure) — used for proj ----
__global__ __launch_bounds__(256) void gemm_nt_proj(
    const u16* __restrict__ A, const u16* __restrict__ Bw,
    float* __restrict__ Cf, const float* __restrict__ bias) {
  constexpr int K = 1024;
  __shared__ __align__(16) u16 sA[128 * 32];
  __shared__ __align__(16) u16 sB[128 * 32];
  const int t = threadIdx.x;
  const int w = t >> 6, l = t & 63;
  const int fr = l & 15, fg = l >> 4;
  const int bm = blockIdx.y * 128, bn = blockIdx.x * 128;
  const int wr = (w >> 1) << 6, wc = (w & 1) << 6;

  f32x4 acc[4][4] = {};

  const int tr = t >> 2, tc = (t & 3) * 8;
  const u16* gA0 = A + (long)(bm + tr) * K + tc;
  const u16* gB0 = Bw + (long)(bn + tr) * K + tc;
  char* sAc = (char*)sA; char* sBc = (char*)sB;
  const int wb = w * 1024;

  for (int k0 = 0; k0 < K; k0 += 32) {
    gl_lds16(gA0 + k0,                 sAc + wb);
    gl_lds16(gA0 + (long)64 * K + k0,  sAc + 4096 + wb);
    gl_lds16(gB0 + k0,                 sBc + wb);
    gl_lds16(gB0 + (long)64 * K + k0,  sBc + 4096 + wb);
    __syncthreads();
    bf16x8 af[4], bf[4];
#pragma unroll
    for (int m = 0; m < 4; ++m)
      af[m] = *(const bf16x8*)&sA[(wr + m * 16 + fr) * 32 + fg * 8];
#pragma unroll
    for (int n = 0; n < 4; ++n)
      bf[n] = *(const bf16x8*)&sB[(wc + n * 16 + fr) * 32 + fg * 8];
#pragma unroll
    for (int m = 0; m < 4; ++m) {
#pragma unroll
      for (int n = 0; n < 4; ++n)
        acc[m][n] = __builtin_amdgcn_mfma_f32_16x16x32_bf16(af[m], bf[n], acc[m][n], 0, 0, 0);
    }
    __syncthreads();
  }

#pragma unroll
  for (int m = 0; m < 4; ++m) {
    const int grow = bm + wr + m * 16 + fg * 4;
#pragma unroll
    for (int n = 0; n < 4; ++n) {
      const int gcol = bn + wc + n * 16 + fr;
      float bv = bias[gcol];
#pragma unroll
      for (int r = 0; r < 4; ++r)
        Cf[(long)(grow + r) * 1024 + gcol] = acc[m][n][r] + bv;
    }
  }
}

// ---------------- flash attention: swapped-QK^T, in-register P ----------
__global__ __launch_bounds__(512, 4) void attn_fused(
    const u16* __restrict__ qk, const u16* __restrict__ vt,
    u16* __restrict__ ao) {
  const int t = threadIdx.x;
  const int w = t >> 6, l = t & 63;
  const int hi = l >> 5, ql = l & 31;
  const int bi = blockIdx.x;
  const int bh = (bi & 7) * 8 + ((bi >> 3) & 7);
  const int qt = bi >> 6;
  const int b = bh >> 4, h = bh & 15;
  const int qbase = qt * 256 + w * 32;

  __shared__ __align__(16) u16 sK[2][4096];
  __shared__ __align__(16) u16 sV[2][4096];
  __shared__ float sRed[8][32];

  bf16x8 qf[4];
  {
    const u16* qb = qk + (long)(b * 2048 + qbase + ql) * 2048 + h * 64 + hi * 8;
#pragma unroll
    for (int c = 0; c < 4; ++c) qf[c] = *(const bf16x8*)(qb + c * 16);
  }

  f32x16 acc0 = {}, acc1 = {};
  float mrow = -__builtin_inff(), lrow = 0.f;

  const int srow = w * 8 + (l >> 3);
  const int schunk = (l & 7) ^ (l >> 3);
  const u16* gKs = qk + (long)(b * 2048 + srow) * 2048 + 1024 + h * 64 + schunk * 8;
  const u16* gVs = vt + (long)(bh * 64 + srow) * 2048 + schunk * 8;
  char* sKc = (char*)sK; char* sVc = (char*)sV;
  const int wb = w * 1024;

  auto STAGE = [&](int buf, int kv0) {
    gl_lds16(gKs + (long)kv0 * 2048, sKc + buf * 8192 + wb);
    gl_lds16(gVs + kv0,              sVc + buf * 8192 + wb);
  };

  STAGE(0, 0);
  __syncthreads();
  int cur = 0;

  for (int ti = 0; ti < 32; ++ti) {
    if (ti < 31) STAGE(cur ^ 1, (ti + 1) * 64);

    f32x16 s0 = {}, s1 = {};
#pragma unroll
    for (int c = 0; c < 4; ++c) {
      bf16x8 kf = *(const bf16x8*)&sK[cur][(0 * 32 + ql) * 64 + (((2 * c + hi) ^ (l & 7)) * 8)];
      s0 = __builtin_amdgcn_mfma_f32_32x32x16_bf16(kf, qf[c], s0, 0, 0, 0);
    }
#pragma unroll
    for (int c = 0; c < 4; ++c) {
      bf16x8 kf = *(const bf16x8*)&sK[cur][(1 * 32 + ql) * 64 + (((2 * c + hi) ^ (l & 7)) * 8)];
      s1 = __builtin_amdgcn_mfma_f32_32x32x16_bf16(kf, qf[c], s1, 0, 0, 0);
    }

    float mloc = s0[0];
#pragma unroll
    for (int r = 1; r < 16; ++r) mloc = fmaxf(mloc, s0[r]);
#pragma unroll
    for (int r = 0; r < 16; ++r) mloc = fmaxf(mloc, s1[r]);
    mloc = fmaxf(mloc, __shfl_xor(mloc, 32));
    float nm = fmaxf(mrow, mloc);
    if (!__all(nm - mrow <= 8.0f)) {
      float al = __builtin_amdgcn_exp2f(mrow - nm);
      lrow *= al;
      mrow = nm;
      if (l < 32) sRed[w][ql] = al;
#pragma unroll
      for (int r = 0; r < 16; ++r) {
        float a2 = sRed[w][(r & 3) + 8 * (r >> 2) + 4 * hi];
        acc0[r] *= a2;
        acc1[r] *= a2;
      }
    }
    float ls = 0.f;
#pragma unroll
    for (int r = 0; r < 16; ++r) { float p = __builtin_amdgcn_exp2f(s0[r] - mrow); s0[r] = p; ls += p; }
#pragma unroll
    for (int r = 0; r < 16; ++r) { float p = __builtin_amdgcn_exp2f(s1[r] - mrow); s1[r] = p; ls += p; }
    ls += __shfl_xor(ls, 32);
    lrow += ls;

    bf16x8 pa[2][2];
    {
      unsigned W[8];
#pragma unroll
      for (int ii = 0; ii < 8; ++ii)
        asm("v_cvt_pk_bf16_f32 %0, %1, %2" : "=v"(W[ii]) : "v"(s0[2 * ii]), "v"(s0[2 * ii + 1]));
      asm("v_permlane32_swap_b32 %0, %1" : "+v"(W[0]), "+v"(W[2]));
      asm("v_permlane32_swap_b32 %0, %1" : "+v"(W[1]), "+v"(W[3]));
      asm("v_permlane32_swap_b32 %0, %1" : "+v"(W[4]), "+v"(W[6]));
      asm("v_permlane32_swap_b32 %0, %1" : "+v"(W[5]), "+v"(W[7]));
      u32x4 f0 = {W[0], W[1], W[2], W[3]}, f1 = {W[4], W[5], W[6], W[7]};
      pa[0][0] = __builtin_bit_cast(bf16x8, f0);
      pa[0][1] = __builtin_bit_cast(bf16x8, f1);
    }
    {
      unsigned W[8];
#pragma unroll
      for (int ii = 0; ii < 8; ++ii)
        asm("v_cvt_pk_bf16_f32 %0, %1, %2" : "=v"(W[ii]) : "v"(s1[2 * ii]), "v"(s1[2 * ii + 1]));
      asm("v_permlane32_swap_b32 %0, %1" : "+v"(W[0]), "+v"(W[2]));
      asm("v_permlane32_swap_b32 %0, %1" : "+v"(W[1]), "+v"(W[3]));
      asm("v_permlane32_swap_b32 %0, %1" : "+v"(W[4]), "+v"(W[6]));
      asm("v_permlane32_swap_b32 %0, %1" : "+v"(W[5]), "+v"(W[7]));
      u32x4 f0 = {W[0], W[1], W[2], W[3]}, f1 = {W[4], W[5], W[6], W[7]};
      pa[1][0] = __builtin_bit_cast(bf16x8, f0);
      pa[1][1] = __builtin_bit_cast(bf16x8, f1);
    }

#pragma unroll
    for (int kt = 0; kt < 2; ++kt) {
#pragma unroll
      for (int kc = 0; kc < 2; ++kc) {
        bf16x8 v0 = *(const bf16x8*)&sV[cur][(0 * 32 + ql) * 64 + (((4 * kt + 2 * kc + hi) ^ (l & 7)) * 8)];
        acc0 = __builtin_amdgcn_mfma_f32_32x32x16_bf16(pa[kt][kc], v0, acc0, 0, 0, 0);
        bf16x8 v1 = *(const bf16x8*)&sV[cur][(1 * 32 + ql) * 64 + (((4 * kt + 2 * kc + hi) ^ (l & 7)) * 8)];
        acc1 = __builtin_amdgcn_mfma_f32_32x32x16_bf16(pa[kt][kc], v1, acc1, 0, 0, 0);
      }
    }
    __syncthreads();
    cur ^= 1;
  }

  if (l < 32) sRed[w][ql] = 1.0f / lrow;
  __builtin_amdgcn_s_waitcnt(0);
#pragma unroll
  for (int r = 0; r < 16; ++r) {
    const int qr = (r & 3) + 8 * (r >> 2) + 4 * hi;
    const float inv = sRed[w][qr];
    u16* ob = ao + (long)(b * 2048 + qbase + qr) * 1024 + h * 64 + ql;
    ob[0]  = cvt_bf16(acc0[r] * inv);
    ob[32] = cvt_bf16(acc1[r] * inv);
  }
}

extern "C" void kernel_launch(void* const* d_in, const int* in_sizes, int n_in,
                              void* d_out, int out_size, void* d_ws, size_t ws_size,
                              hipStream_t stream) {
  const float* x     = (const float*)d_in[0];   // [4,2048,1024]
  const float* wqkv  = (const float*)d_in[1];   // [3072,1024]
  const float* wproj = (const float*)d_in[2];   // [1024,1024]
  const float* bproj = (const float*)d_in[3];   // [1024]
  float* out = (float*)d_out;

  u16* ws    = (u16*)d_ws;
  u16* xb    = ws;                    // 8388608  : x bf16 (dead after gemm1)
  u16* wqkvb = xb + 8388608;          // 3145728  : w_qkv bf16
  u16* wpb   = wqkvb + 3145728;       // 1048576  : w_proj bf16
  u16* qkb   = wpb + 1048576;         // 16777216 : [B*N][2048] Q|K bf16
  u16* vtb   = qkb + 16777216;        // 8388608  : [bh*64+d][2048] V^T bf16
  u16* aob   = xb;                    // aliases xb (x dead before attn writes)
  // peak 37748736 u16 = 75.5 MB

  cast_f32_bf16<<<4096, 256, 0, stream>>>(x, xb);
  cast_f32_bf16<<<1536, 256, 0, stream>>>(wqkv, wqkvb);
  cast_f32_bf16<<<512, 256, 0, stream>>>(wproj, wpb);

  gemm1_8p<<<384, 512, 0, stream>>>(xb, wqkvb, qkb, vtb);
  attn_fused<<<512, 512, 0, stream>>>(qkb, vtb, aob);
  gemm_nt_proj<<<dim3(8, 64), 256, 0, stream>>>(aob, wpb, out, bproj);
}